// Round 2
// baseline (190.068 us; speedup 1.0000x reference)
//
#include <hip/hip_runtime.h>

#define NTOK 65536
#define DIN 128
#define DH 256
#define DOUT 128
#define NEXP 8
#define NPAIR 28
#define CAP 12288
#define TBL 1031      // 16-token tiles, 4 per block: ceil((65536/16 + 28)/4)
#define TAUF 5.0f
#define CSTRIDE 32    // cnt padded: one counter per 128 B

typedef __attribute__((ext_vector_type(8))) short short8;
typedef __attribute__((ext_vector_type(4))) float f32x4;

// ---- workspace layout (bytes) ----
#define OFF_CNT  0                              // 28 ints @ stride 32 ints
#define OFF_WG   4096                           // 1024 f32
#define OFF_BG   8192                           // 8 f32
#define OFF_W1F  8448                           // 8*128*256 bf16 = 524288
#define OFF_W2F  (OFF_W1F + NEXP*DIN*DH*2)      // 524288
#define OFF_L    (OFF_W2F + NEXP*DH*DOUT*2)     // 28*12288*16 = 5505024
// total ~6.6 MB

__device__ __forceinline__ unsigned short f2bf(float f) {
  union { float f; unsigned u; } v; v.f = f;
  unsigned u = v.u;
  return (unsigned short)((u + 0x7FFFu + ((u >> 16) & 1u)) >> 16);
}

// ---- kernel 1: weight conversion (blocks 0..95) + gate fuse + cnt/aux zero (block 96) ----
__global__ void k_prep(const float* __restrict__ W1, const float* __restrict__ W2,
                       unsigned short* __restrict__ W1F, unsigned short* __restrict__ W2F,
                       const float* __restrict__ Wp, const float* __restrict__ bp,
                       const float* __restrict__ Ee, float* __restrict__ Wg,
                       float* __restrict__ bg, int* __restrict__ cnt,
                       float* __restrict__ aux) {
  __shared__ float sl[8704];                    // >= 32*257 for conversion path
  int b = blockIdx.x, t = threadIdx.x;
  if (b == 96) {
    // stage Wp (8192 f) + Ee (512 f) into LDS, then compute Wg = Wp@Ee fused
    for (int i = 0; i < 32; i++) sl[t + i * 256] = Wp[t + i * 256];
    sl[8192 + t] = Ee[t];
    sl[8448 + t] = Ee[256 + t];
    __syncthreads();
    for (int i = 0; i < 4; i++) {
      int o = t + i * 256;
      int k = o >> 3, e = o & 7;
      float s = 0.f;
      #pragma unroll 8
      for (int l = 0; l < 64; l++) s += sl[k * 64 + l] * sl[8192 + l * 8 + e];
      Wg[o] = s;
    }
    if (t < 8) {
      float s = 0.f;
      for (int l = 0; l < 64; l++) s += bp[l] * sl[8192 + l * 8 + t];
      bg[t] = s;
    }
    if (t < NPAIR) cnt[t * CSTRIDE] = 0;
    if (t == 255) aux[0] = 0.f;
    return;
  }
  const float* src; unsigned short* dst;
  int stride, iters, cshift;
  if (b < 32) {
    int e = b >> 2, kk = b & 3;
    src = W1 + e * (DIN * DH) + kk * 32 * DH;
    dst = W1F + e * (DIN * DH) + kk * (32 * DH);
    stride = 257; iters = 32; cshift = 8;           // 32 x 256 slab
  } else {
    int bb = b - 32;
    int e = bb >> 3, kk = bb & 7;
    src = W2 + e * (DH * DOUT) + kk * 32 * DOUT;
    dst = W2F + e * (DH * DOUT) + kk * (32 * DOUT);
    stride = 129; iters = 16; cshift = 7;           // 32 x 128 slab
  }
  int ncols_m1 = (1 << cshift) - 1;
  for (int i = 0; i < iters; i++) {
    int idx = t + i * 256;
    int r = idx >> cshift, c = idx & ncols_m1;
    sl[r * stride + c] = src[idx];
  }
  __syncthreads();
  for (int i = 0; i < iters; i++) {
    int o = t + i * 256;                            // o = n*32 + c : B-frag linear
    int n = o >> 5, cc = o & 31;
    dst[o] = f2bf(sl[cc * stride + n]);
  }
}

// ---- kernel 2: gate v2 — thread-per-token (256 blocks x 256 tokens).
// x rows -> registers (no LDS staging, no bank conflicts); Wg broadcast from LDS.
// All 256 lanes busy through sigmoid/top-2. Atomic chains: 256 per counter (was 1024). ----
__global__ void __launch_bounds__(256) k_gate(
    const float* __restrict__ x, const float* __restrict__ Wg, const float* __restrict__ bg,
    float* __restrict__ pout, int* __restrict__ cnt, uint4* __restrict__ lst) {
  __shared__ float wgl[1024];
  __shared__ float bgl[8];
  __shared__ int lc[NPAIR], lb[NPAIR];
  int t = threadIdx.x, b = blockIdx.x;
  int tok = b * 256 + t;
  *(float4*)&wgl[t * 4] = ((const float4*)Wg)[t];
  if (t < 8) bgl[t] = bg[t];
  if (t < NPAIR) lc[t] = 0;
  __syncthreads();
  float acc[8];
  #pragma unroll
  for (int e = 0; e < 8; e++) acc[e] = bgl[e];
  const float4* xr = (const float4*)(x + (size_t)tok * DIN);
  #pragma unroll 4
  for (int i = 0; i < 32; i++) {
    float4 xv = xr[i];
    #pragma unroll
    for (int j = 0; j < 4; j++) {
      float xs_ = (j == 0) ? xv.x : (j == 1) ? xv.y : (j == 2) ? xv.z : xv.w;
      float4 wa = *(const float4*)&wgl[(i * 4 + j) * 8];
      float4 wb = *(const float4*)&wgl[(i * 4 + j) * 8 + 4];
      acc[0] += xs_ * wa.x; acc[1] += xs_ * wa.y; acc[2] += xs_ * wa.z; acc[3] += xs_ * wa.w;
      acc[4] += xs_ * wb.x; acc[5] += xs_ * wb.y; acc[6] += xs_ * wb.z; acc[7] += xs_ * wb.w;
    }
  }
  float p[8];
  #pragma unroll
  for (int e = 0; e < 8; e++) p[e] = 1.f / (1.f + expf(-acc[e] / TAUF));
  float* prow = pout + (size_t)tok * 8;
  #pragma unroll
  for (int e = 0; e < 8; e++) prow[e] = p[e];
  int i0 = 0; float v0 = -1.f;
  #pragma unroll
  for (int e = 0; e < 8; e++) if (p[e] > v0) { v0 = p[e]; i0 = e; }
  int i1 = -1; float v1 = -1.f;
  #pragma unroll
  for (int e = 0; e < 8; e++) if (e != i0 && p[e] > v1) { v1 = p[e]; i1 = e; }
  float s = v0 + v1 + 1e-10f;
  float w0 = v0 / s, w1 = v1 / s;
  int eA, eB; float wA, wB;
  if (i0 < i1) { eA = i0; eB = i1; wA = w0; wB = w1; }
  else         { eA = i1; eB = i0; wA = w1; wB = w0; }
  int pid = 7 * eA - (eA * (eA - 1)) / 2 + (eB - eA - 1);   // 28 unordered pairs
  union { float f; unsigned u; } ua, ub; ua.f = wA; ub.f = wB;
  unsigned wAb = ua.u, wBb = ub.u;
  unsigned pos = (unsigned)atomicAdd(&lc[pid], 1);   // LDS atomic
  __syncthreads();
  if (t < NPAIR) lb[t] = atomicAdd(&cnt[t * CSTRIDE], lc[t]);
  __syncthreads();
  int gi = lb[pid] + (int)pos;
  if (gi < CAP) lst[pid * CAP + gi] = make_uint4((unsigned)tok, wAb, wBb, 0u);
}

// ---- kernel 3: expert v3 — BARRIER-FREE. One wave = one independent 16-token tile
// with private xs/hs LDS slabs; zero __syncthreads, all ordering same-wave lgkmcnt.
// Same 16 MFMA/token (wave computes its full N=256 hidden, N=128 out).
// DH split in halves so hs slab = 16x128 and GEMM2 overlaps GEMM1 per half. ----
__global__ void __launch_bounds__(256, 3) k_expert(
    const float* __restrict__ x,
    const unsigned short* __restrict__ W1F, const unsigned short* __restrict__ W2F,
    const float* __restrict__ b1, const float* __restrict__ b2,
    const int* __restrict__ cnt, const uint4* __restrict__ lst,
    float* __restrict__ out) {
  __shared__ unsigned short xsA[4][16 * 136];   // 4 x 4352 B
  __shared__ unsigned short hsA[4][16 * 136];   // 4 x 4352 B (half-H per wave)
  __shared__ int tokA[4][16];
  __shared__ float wabA[4][32];
  int t = threadIdx.x;
  int w = t >> 6, lane = t & 63;
  int q = lane >> 4, n16 = lane & 15;
  unsigned short* xsw = xsA[w];
  unsigned short* hsw = hsA[w];
  int* tokw = tokA[w];
  float* wabw = wabA[w];

  int tileId = blockIdx.x * 4 + w;
  int bsel = -1, tIn = 0, cum = 0, cntb = 0;
  #pragma unroll
  for (int bb = 0; bb < NPAIR; bb++) {
    int c = cnt[bb * CSTRIDE]; c = (c > CAP) ? CAP : c;
    int tb = (c + 15) >> 4;
    if (bsel < 0 && tileId < cum + tb) { bsel = bb; tIn = tileId - cum; cntb = c; }
    cum += tb;
  }
  if (bsel < 0) return;
  int eA = 0, eB = 1;
  { int r = bsel;
    #pragma unroll
    for (int a = 0; a < 7; a++) { int span = 7 - a; if (r < span) { eA = a; eB = a + 1 + r; break; } r -= span; } }
  int start = tIn * 16;
  int cvalid = min(16, cntb - start);

  if (lane < 16) {
    if (lane < cvalid) {
      uint4 en = lst[bsel * CAP + start + lane];
      tokw[lane] = (int)en.x;
      union { unsigned u; float f; } ua, ub; ua.u = en.y; ub.u = en.z;
      wabw[lane] = ua.f; wabw[16 + lane] = ub.f;
    } else { tokw[lane] = 0; wabw[lane] = 0.f; wabw[16 + lane] = 0.f; }
  }
  // gather 16 x rows -> bf16 LDS (per-wave; same-wave lgkmcnt ordering only)
  #pragma unroll
  for (int i = 0; i < 8; i++) {
    int idx = i * 64 + lane;
    int r = idx >> 5, c4 = idx & 31;
    float4 f = *(const float4*)(x + (size_t)tokw[r] * DIN + c4 * 4);
    unsigned u0 = (unsigned)f2bf(f.x) | ((unsigned)f2bf(f.y) << 16);
    unsigned u1 = (unsigned)f2bf(f.z) | ((unsigned)f2bf(f.w) << 16);
    *(uint2*)(xsw + r * 136 + c4 * 4) = make_uint2(u0, u1);
  }

  const f32x4 vz = {0.f, 0.f, 0.f, 0.f};
  f32x4 accO[8];
  #pragma unroll
  for (int pass = 0; pass < 2; pass++) {
    int e = pass ? eB : eA;
    const unsigned short* W1e = W1F + e * (DIN * DH);
    const unsigned short* W2e = W2F + e * (DH * DOUT);
    f32x4 acc2[8];
    #pragma unroll
    for (int i = 0; i < 8; i++) acc2[i] = vz;
    #pragma unroll
    for (int h = 0; h < 2; h++) {
      // GEMM1 half: H[:, h*128 .. +128) = relu(X @ W1[:, half] + b1)
      f32x4 acc1[8];
      #pragma unroll
      for (int i = 0; i < 8; i++) acc1[i] = vz;
      #pragma unroll
      for (int kk = 0; kk < 4; kk++) {
        short8 av = *(const short8*)(xsw + n16 * 136 + kk * 32 + q * 8);
        const unsigned short* B1 = W1e + kk * 8192 + (h * 128 + n16) * 32 + q * 8;
        #pragma unroll
        for (int nt = 0; nt < 8; nt++) {
          short8 bv = *(const short8*)(B1 + nt * 512);
          acc1[nt] = __builtin_amdgcn_mfma_f32_16x16x32_bf16(av, bv, acc1[nt], 0, 0, 0);
        }
      }
      #pragma unroll
      for (int nt = 0; nt < 8; nt++) {
        float bb1 = b1[e * DH + h * 128 + nt * 16 + n16];
        #pragma unroll
        for (int r = 0; r < 4; r++) {
          float v = fmaxf(acc1[nt][r] + bb1, 0.f);
          hsw[(q * 4 + r) * 136 + nt * 16 + n16] = f2bf(v);
        }
      }
      // GEMM2 partial-K over this half (acc2 persists across halves)
      #pragma unroll
      for (int kk2 = 0; kk2 < 4; kk2++) {
        short8 a2 = *(const short8*)(hsw + n16 * 136 + kk2 * 32 + q * 8);
        const unsigned short* B2 = W2e + (h * 4 + kk2) * 4096 + n16 * 32 + q * 8;
        #pragma unroll
        for (int nt2 = 0; nt2 < 8; nt2++) {
          short8 bv2 = *(const short8*)(B2 + nt2 * 512);
          acc2[nt2] = __builtin_amdgcn_mfma_f32_16x16x32_bf16(a2, bv2, acc2[nt2], 0, 0, 0);
        }
      }
    }
    #pragma unroll
    for (int nt2 = 0; nt2 < 8; nt2++) {
      float bb2 = b2[e * DOUT + nt2 * 16 + n16];
      #pragma unroll
      for (int r = 0; r < 4; r++) {
        float wv = wabw[pass * 16 + q * 4 + r];
        float v = (acc2[nt2][r] + bb2) * wv;
        if (pass) accO[nt2][r] += v;
        else      accO[nt2][r] = v;
      }
    }
  }
  #pragma unroll
  for (int r = 0; r < 4; r++) {
    int row = q * 4 + r;
    if (row < cvalid) {
      float* orow = out + (size_t)tokw[row] * DOUT + n16;
      #pragma unroll
      for (int nt2 = 0; nt2 < 8; nt2++) orow[nt2 * 16] = accO[nt2][r];
    }
  }
}

extern "C" void kernel_launch(void* const* d_in, const int* in_sizes, int n_in,
                              void* d_out, int out_size, void* d_ws, size_t ws_size,
                              hipStream_t stream) {
  const float* x  = (const float*)d_in[0];
  const float* Wp = (const float*)d_in[1];
  const float* bp = (const float*)d_in[2];
  const float* Ee = (const float*)d_in[3];
  const float* W1 = (const float*)d_in[4];
  const float* b1 = (const float*)d_in[5];
  const float* W2 = (const float*)d_in[6];
  const float* b2 = (const float*)d_in[7];
  float* out = (float*)d_out;
  char* ws = (char*)d_ws;
  int* cnt = (int*)(ws + OFF_CNT);
  float* Wg = (float*)(ws + OFF_WG);
  float* bg = (float*)(ws + OFF_BG);
  unsigned short* W1F = (unsigned short*)(ws + OFF_W1F);
  unsigned short* W2F = (unsigned short*)(ws + OFF_W2F);
  uint4* lst = (uint4*)(ws + OFF_L);
  float* aux = out + (size_t)NTOK * DOUT;     // scalar output
  float* pout = aux + 1;                      // p_open [N,8]

  k_prep<<<97, 256, 0, stream>>>(W1, W2, W1F, W2F, Wp, bp, Ee, Wg, bg, cnt, aux);
  k_gate<<<NTOK / 256, 256, 0, stream>>>(x, Wg, bg, pout, cnt, lst);
  k_expert<<<TBL, 256, 0, stream>>>(x, W1F, W2F, b1, b2, cnt, lst, out);
}

// Round 3
// 154.992 us; speedup vs baseline: 1.2263x; 1.2263x over previous
//
#include <hip/hip_runtime.h>

#define NTOK 65536
#define DIN 128
#define DH 256
#define DOUT 128
#define NEXP 8
#define NPAIR 28
#define CAP 12288
#define NBEXP 256     // persistent expert blocks, 1 per CU
#define TAUF 5.0f
#define CSTRIDE 32    // cnt padded: one counter per 128 B

typedef __attribute__((ext_vector_type(8))) short short8;
typedef __attribute__((ext_vector_type(4))) float f32x4;

// ---- workspace layout (bytes) ----
#define OFF_CNT  0                              // 28 ints @ stride 32 ints
#define OFF_WG   4096                           // 1024 f32
#define OFF_BG   8192                           // 8 f32
#define OFF_W1F  8448                           // 8*128*256 bf16 = 524288
#define OFF_W2F  (OFF_W1F + NEXP*DIN*DH*2)      // 524288
#define OFF_L    (OFF_W2F + NEXP*DH*DOUT*2)     // 28*12288*16 = 5505024
// total ~6.6 MB

__device__ __forceinline__ unsigned short f2bf(float f) {
  union { float f; unsigned u; } v; v.f = f;
  unsigned u = v.u;
  return (unsigned short)((u + 0x7FFFu + ((u >> 16) & 1u)) >> 16);
}

// ---- kernel 1: weight conversion (blocks 0..95) + gate fuse + cnt/aux zero (block 96) ----
__global__ void k_prep(const float* __restrict__ W1, const float* __restrict__ W2,
                       unsigned short* __restrict__ W1F, unsigned short* __restrict__ W2F,
                       const float* __restrict__ Wp, const float* __restrict__ bp,
                       const float* __restrict__ Ee, float* __restrict__ Wg,
                       float* __restrict__ bg, int* __restrict__ cnt,
                       float* __restrict__ aux) {
  __shared__ float sl[8704];                    // >= 32*257 for conversion path
  int b = blockIdx.x, t = threadIdx.x;
  if (b == 96) {
    // stage Wp (8192 f) + Ee (512 f) into LDS, then compute Wg = Wp@Ee fused
    for (int i = 0; i < 32; i++) sl[t + i * 256] = Wp[t + i * 256];
    sl[8192 + t] = Ee[t];
    sl[8448 + t] = Ee[256 + t];
    __syncthreads();
    for (int i = 0; i < 4; i++) {
      int o = t + i * 256;
      int k = o >> 3, e = o & 7;
      float s = 0.f;
      #pragma unroll 8
      for (int l = 0; l < 64; l++) s += sl[k * 64 + l] * sl[8192 + l * 8 + e];
      Wg[o] = s;
    }
    if (t < 8) {
      float s = 0.f;
      for (int l = 0; l < 64; l++) s += bp[l] * sl[8192 + l * 8 + t];
      bg[t] = s;
    }
    if (t < NPAIR) cnt[t * CSTRIDE] = 0;
    if (t == 255) aux[0] = 0.f;
    return;
  }
  const float* src; unsigned short* dst;
  int stride, iters, cshift;
  if (b < 32) {
    int e = b >> 2, kk = b & 3;
    src = W1 + e * (DIN * DH) + kk * 32 * DH;
    dst = W1F + e * (DIN * DH) + kk * (32 * DH);
    stride = 257; iters = 32; cshift = 8;           // 32 x 256 slab
  } else {
    int bb = b - 32;
    int e = bb >> 3, kk = bb & 7;
    src = W2 + e * (DH * DOUT) + kk * 32 * DOUT;
    dst = W2F + e * (DH * DOUT) + kk * (32 * DOUT);
    stride = 129; iters = 16; cshift = 7;           // 32 x 128 slab
  }
  int ncols_m1 = (1 << cshift) - 1;
  for (int i = 0; i < iters; i++) {
    int idx = t + i * 256;
    int r = idx >> cshift, c = idx & ncols_m1;
    sl[r * stride + c] = src[idx];
  }
  __syncthreads();
  for (int i = 0; i < iters; i++) {
    int o = t + i * 256;                            // o = n*32 + c : B-frag linear
    int n = o >> 5, cc = o & 31;
    dst[o] = f2bf(sl[cc * stride + n]);
  }
}

// ---- kernel 2: gate — thread-per-token (256 blocks x 256 tokens) ----
__global__ void __launch_bounds__(256) k_gate(
    const float* __restrict__ x, const float* __restrict__ Wg, const float* __restrict__ bg,
    float* __restrict__ pout, int* __restrict__ cnt, uint4* __restrict__ lst) {
  __shared__ float wgl[1024];
  __shared__ float bgl[8];
  __shared__ int lc[NPAIR], lb[NPAIR];
  int t = threadIdx.x, b = blockIdx.x;
  int tok = b * 256 + t;
  *(float4*)&wgl[t * 4] = ((const float4*)Wg)[t];
  if (t < 8) bgl[t] = bg[t];
  if (t < NPAIR) lc[t] = 0;
  __syncthreads();
  float acc[8];
  #pragma unroll
  for (int e = 0; e < 8; e++) acc[e] = bgl[e];
  const float4* xr = (const float4*)(x + (size_t)tok * DIN);
  #pragma unroll 4
  for (int i = 0; i < 32; i++) {
    float4 xv = xr[i];
    #pragma unroll
    for (int j = 0; j < 4; j++) {
      float xs_ = (j == 0) ? xv.x : (j == 1) ? xv.y : (j == 2) ? xv.z : xv.w;
      float4 wa = *(const float4*)&wgl[(i * 4 + j) * 8];
      float4 wb = *(const float4*)&wgl[(i * 4 + j) * 8 + 4];
      acc[0] += xs_ * wa.x; acc[1] += xs_ * wa.y; acc[2] += xs_ * wa.z; acc[3] += xs_ * wa.w;
      acc[4] += xs_ * wb.x; acc[5] += xs_ * wb.y; acc[6] += xs_ * wb.z; acc[7] += xs_ * wb.w;
    }
  }
  float p[8];
  #pragma unroll
  for (int e = 0; e < 8; e++) p[e] = 1.f / (1.f + expf(-acc[e] / TAUF));
  float* prow = pout + (size_t)tok * 8;
  #pragma unroll
  for (int e = 0; e < 8; e++) prow[e] = p[e];
  int i0 = 0; float v0 = -1.f;
  #pragma unroll
  for (int e = 0; e < 8; e++) if (p[e] > v0) { v0 = p[e]; i0 = e; }
  int i1 = -1; float v1 = -1.f;
  #pragma unroll
  for (int e = 0; e < 8; e++) if (e != i0 && p[e] > v1) { v1 = p[e]; i1 = e; }
  float s = v0 + v1 + 1e-10f;
  float w0 = v0 / s, w1 = v1 / s;
  int eA, eB; float wA, wB;
  if (i0 < i1) { eA = i0; eB = i1; wA = w0; wB = w1; }
  else         { eA = i1; eB = i0; wA = w1; wB = w0; }
  int pid = 7 * eA - (eA * (eA - 1)) / 2 + (eB - eA - 1);   // 28 unordered pairs
  union { float f; unsigned u; } ua, ub; ua.f = wA; ub.f = wB;
  unsigned wAb = ua.u, wBb = ub.u;
  unsigned pos = (unsigned)atomicAdd(&lc[pid], 1);   // LDS atomic
  __syncthreads();
  if (t < NPAIR) lb[t] = atomicAdd(&cnt[t * CSTRIDE], lc[t]);
  __syncthreads();
  int gi = lb[pid] + (int)pos;
  if (gi < CAP) lst[pid * CAP + gi] = make_uint4((unsigned)tok, wAb, wBb, 0u);
}

// ---- kernel 3: expert v4 — bucket-persistent blocks, weight-stationary registers.
// 256 blocks x 512 threads (8 waves). Waves 0-3 = expert A, 4-7 = expert B,
// each wave owns quarter qw of hidden (64 cols, GEMM1) and out (32 cols, GEMM2);
// its W1/W2 panels live in VGPRs (128 regs), loaded once per pair-bucket.
// Block processes a contiguous range of global 32-token tiles; xs double-buffered,
// next tile's lst + x-gather issued early (hidden under MFMA). A/B combined via
// LDS staging (ostg aliases hsB). 4 barriers/tile. ----
__global__ void __launch_bounds__(512, 2) k_expert(
    const float* __restrict__ x,
    const unsigned short* __restrict__ W1F, const unsigned short* __restrict__ W2F,
    const float* __restrict__ b1, const float* __restrict__ b2,
    const int* __restrict__ cnt, const uint4* __restrict__ lst,
    float* __restrict__ out) {
  __shared__ int cs[NPAIR];
  __shared__ __align__(16) unsigned short xsb[2][32 * 136];   // 2 x 8704 B
  __shared__ __align__(16) unsigned short hsA[32 * 264];      // 16896 B
  __shared__ __align__(16) unsigned short hsB[32 * 264];      // 16896 B; doubles as ostg
  __shared__ int toksL[2][32];
  __shared__ float wabL[2][64];                               // [par][0..31]=wA, [32..63]=wB
  int t = threadIdx.x;
  int w = t >> 6, lane = t & 63;
  int q = lane >> 4, n16 = lane & 15;
  int half = w >> 2, qw = w & 3;   // half: 0=expert A, 1=expert B
  float* ostg = (float*)hsB;       // 32 x 132 f32 = 16896 B (exact alias)
  unsigned short* hsw = half ? hsB : hsA;

  if (t < NPAIR) { int c = cnt[t * CSTRIDE]; cs[t] = (c > CAP) ? CAP : c; }
  __syncthreads();
  int TT = 0;
  #pragma unroll
  for (int bb = 0; bb < NPAIR; bb++) TT += (cs[bb] + 31) >> 5;
  int T = (TT + NBEXP - 1) / NBEXP;
  int g = (int)blockIdx.x * T;
  int gEnd = min(TT, g + T);
  if (g >= gEnd) return;

  auto resolve = [&](int gid, int& bsel, int& start, int& cval) {
    int cum = 0; bsel = 0; start = 0; cval = 0;
    #pragma unroll
    for (int bb = 0; bb < NPAIR; bb++) {
      int tb = (cs[bb] + 31) >> 5;
      if (gid >= cum && gid < cum + tb) {
        bsel = bb; start = (gid - cum) * 32; cval = min(32, cs[bb] - start);
      }
      cum += tb;
    }
  };
  auto pairExp = [&](int bsel, int& eA, int& eB) {
    eA = 0; eB = 1; int r = bsel;
    #pragma unroll
    for (int a = 0; a < 7; a++) {
      int span = 7 - a;
      if (r < span) { eA = a; eB = a + 1 + r; return; }
      r -= span;
    }
  };

  short8 bf1[16], bf2[16];
  float b1v[4], b2v[2];
  auto loadW = [&](int eA, int eB) {
    int ew = half ? eB : eA;
    const unsigned short* W1e = W1F + ew * (DIN * DH);
    #pragma unroll
    for (int kk = 0; kk < 4; kk++)
      #pragma unroll
      for (int nt = 0; nt < 4; nt++)
        bf1[kk * 4 + nt] = *(const short8*)(W1e + kk * 8192 + (qw * 64 + nt * 16 + n16) * 32 + q * 8);
    const unsigned short* W2e = W2F + ew * (DH * DOUT);
    #pragma unroll
    for (int kk = 0; kk < 8; kk++)
      #pragma unroll
      for (int nt = 0; nt < 2; nt++)
        bf2[kk * 2 + nt] = *(const short8*)(W2e + kk * 4096 + (qw * 32 + nt * 16 + n16) * 32 + q * 8);
    #pragma unroll
    for (int nt = 0; nt < 4; nt++) b1v[nt] = b1[ew * DH + qw * 64 + nt * 16 + n16];
    #pragma unroll
    for (int nt = 0; nt < 2; nt++) b2v[nt] = b2[ew * DOUT + qw * 32 + nt * 16 + n16];
  };
  auto storex = [&](int par, int row, int c4, float4 f) {
    unsigned u0 = (unsigned)f2bf(f.x) | ((unsigned)f2bf(f.y) << 16);
    unsigned u1 = (unsigned)f2bf(f.z) | ((unsigned)f2bf(f.w) << 16);
    *(uint2*)(&xsb[par][row * 136 + c4 * 4]) = make_uint2(u0, u1);
  };

  // ---- prologue: tile g ----
  int bsel, start, cval;
  resolve(g, bsel, start, cval);
  int eA, eB; pairExp(bsel, eA, eB);
  loadW(eA, eB);
  if (t < 32) {
    uint4 en = make_uint4(0u, 0u, 0u, 0u);
    if (t < cval) en = lst[bsel * CAP + start + t];
    toksL[0][t] = (int)en.x;
    union { unsigned u; float f; } ua, ub; ua.u = en.y; ub.u = en.z;
    wabL[0][t] = (t < cval) ? ua.f : 0.f;
    wabL[0][32 + t] = (t < cval) ? ub.f : 0.f;
  }
  __syncthreads();
  {
    int row0 = t >> 5, c4 = t & 31;
    float4 f0 = *(const float4*)(x + (size_t)toksL[0][row0] * DIN + c4 * 4);
    float4 f1 = *(const float4*)(x + (size_t)toksL[0][16 + row0] * DIN + c4 * 4);
    storex(0, row0, c4, f0);
    storex(0, 16 + row0, c4, f1);
  }
  __syncthreads();

  const f32x4 vz = {0.f, 0.f, 0.f, 0.f};
  int p = 0;
  for (; g < gEnd; ++g) {
    int hasNext = (g + 1 < gEnd);
    int bsel1 = 0, start1 = 0, cval1 = 0;
    if (hasNext) resolve(g + 1, bsel1, start1, cval1);
    // [1] issue next tile's list load (wave 0)
    uint4 ldn = make_uint4(0u, 0u, 0u, 0u);
    if (hasNext && t < 32 && t < cval1) ldn = lst[bsel1 * CAP + start1 + t];
    __builtin_amdgcn_sched_barrier(0);
    // [2] GEMM1: H = relu(X @ W1[ew] + b1), own 64 hidden cols
    {
      f32x4 acc1[2][4];
      #pragma unroll
      for (int mt = 0; mt < 2; mt++)
        #pragma unroll
        for (int nt = 0; nt < 4; nt++) acc1[mt][nt] = vz;
      #pragma unroll
      for (int kk = 0; kk < 4; kk++) {
        short8 a[2];
        #pragma unroll
        for (int mt = 0; mt < 2; mt++)
          a[mt] = *(const short8*)(&xsb[p][(mt * 16 + n16) * 136 + kk * 32 + q * 8]);
        #pragma unroll
        for (int nt = 0; nt < 4; nt++)
          #pragma unroll
          for (int mt = 0; mt < 2; mt++)
            acc1[mt][nt] = __builtin_amdgcn_mfma_f32_16x16x32_bf16(a[mt], bf1[kk * 4 + nt], acc1[mt][nt], 0, 0, 0);
      }
      #pragma unroll
      for (int mt = 0; mt < 2; mt++)
        #pragma unroll
        for (int nt = 0; nt < 4; nt++)
          #pragma unroll
          for (int r = 0; r < 4; r++)
            hsw[(mt * 16 + q * 4 + r) * 264 + qw * 64 + nt * 16 + n16] =
                f2bf(fmaxf(acc1[mt][nt][r] + b1v[nt], 0.f));
    }
    // [3] stage next tile's toks/wab into LDS
    if (hasNext && t < 32) {
      toksL[p ^ 1][t] = (int)ldn.x;
      union { unsigned u; float f; } ua, ub; ua.u = ldn.y; ub.u = ldn.z;
      wabL[p ^ 1][t] = (t < cval1) ? ua.f : 0.f;
      wabL[p ^ 1][32 + t] = (t < cval1) ? ub.f : 0.f;
    }
    __syncthreads();                                   // [4] hs + next-toks ready
    // [5] issue next tile's x gather (latency hides under GEMM2)
    float4 f0, f1;
    int row0 = t >> 5, c4 = t & 31;
    if (hasNext) {
      f0 = *(const float4*)(x + (size_t)toksL[p ^ 1][row0] * DIN + c4 * 4);
      f1 = *(const float4*)(x + (size_t)toksL[p ^ 1][16 + row0] * DIN + c4 * 4);
    }
    __builtin_amdgcn_sched_barrier(0);
    // [6] GEMM2: acc2 = H(own expert) @ W2[ew], own 32 out cols, all 32 rows
    f32x4 acc2[2][2];
    #pragma unroll
    for (int m = 0; m < 2; m++)
      #pragma unroll
      for (int nt = 0; nt < 2; nt++) acc2[m][nt] = vz;
    #pragma unroll
    for (int kk = 0; kk < 8; kk++) {
      short8 a2[2];
      #pragma unroll
      for (int m = 0; m < 2; m++)
        a2[m] = *(const short8*)(&hsw[(m * 16 + n16) * 264 + kk * 32 + q * 8]);
      #pragma unroll
      for (int nt = 0; nt < 2; nt++)
        #pragma unroll
        for (int m = 0; m < 2; m++)
          acc2[m][nt] = __builtin_amdgcn_mfma_f32_16x16x32_bf16(a2[m], bf2[kk * 2 + nt], acc2[m][nt], 0, 0, 0);
    }
    __syncthreads();                                   // [6.5] hsB reads done before ostg overwrite
    // [7] A-waves stage wA*(out_A) into ostg
    if (half == 0) {
      #pragma unroll
      for (int m = 0; m < 2; m++)
        #pragma unroll
        for (int r = 0; r < 4; r++) {
          int row = m * 16 + q * 4 + r;
          float wv = wabL[p][row];
          #pragma unroll
          for (int nt = 0; nt < 2; nt++)
            ostg[row * 132 + qw * 32 + nt * 16 + n16] = (acc2[m][nt][r] + b2v[nt]) * wv;
        }
    }
    __syncthreads();                                   // [8] ostg ready
    // [9] B-waves combine + store
    if (half == 1) {
      #pragma unroll
      for (int m = 0; m < 2; m++)
        #pragma unroll
        for (int r = 0; r < 4; r++) {
          int row = m * 16 + q * 4 + r;
          if (row < cval) {
            float wv = wabL[p][32 + row];
            float* orow = out + (size_t)toksL[p][row] * DOUT + qw * 32 + n16;
            orow[0]  = ostg[row * 132 + qw * 32 + n16]      + (acc2[m][0][r] + b2v[0]) * wv;
            orow[16] = ostg[row * 132 + qw * 32 + 16 + n16] + (acc2[m][1][r] + b2v[1]) * wv;
          }
        }
    }
    // [10] write next tile's xs (gather loads have drained under GEMM2)
    if (hasNext) {
      storex(p ^ 1, row0, c4, f0);
      storex(p ^ 1, 16 + row0, c4, f1);
    }
    // [11] bucket boundary: reload weight registers (rare)
    if (hasNext && bsel1 != bsel) {
      int eA1, eB1; pairExp(bsel1, eA1, eB1);
      loadW(eA1, eB1);
    }
    bsel = bsel1; cval = cval1;
    __syncthreads();                                   // [12] xs[next] ready
    p ^= 1;
  }
}

extern "C" void kernel_launch(void* const* d_in, const int* in_sizes, int n_in,
                              void* d_out, int out_size, void* d_ws, size_t ws_size,
                              hipStream_t stream) {
  const float* x  = (const float*)d_in[0];
  const float* Wp = (const float*)d_in[1];
  const float* bp = (const float*)d_in[2];
  const float* Ee = (const float*)d_in[3];
  const float* W1 = (const float*)d_in[4];
  const float* b1 = (const float*)d_in[5];
  const float* W2 = (const float*)d_in[6];
  const float* b2 = (const float*)d_in[7];
  float* out = (float*)d_out;
  char* ws = (char*)d_ws;
  int* cnt = (int*)(ws + OFF_CNT);
  float* Wg = (float*)(ws + OFF_WG);
  float* bg = (float*)(ws + OFF_BG);
  unsigned short* W1F = (unsigned short*)(ws + OFF_W1F);
  unsigned short* W2F = (unsigned short*)(ws + OFF_W2F);
  uint4* lst = (uint4*)(ws + OFF_L);
  float* aux = out + (size_t)NTOK * DOUT;     // scalar output
  float* pout = aux + 1;                      // p_open [N,8]

  k_prep<<<97, 256, 0, stream>>>(W1, W2, W1F, W2F, Wp, bp, Ee, Wg, bg, cnt, aux);
  k_gate<<<NTOK / 256, 256, 0, stream>>>(x, Wg, bg, pout, cnt, lst);
  k_expert<<<NBEXP, 512, 0, stream>>>(x, W1F, W2F, b1, b2, cnt, lst, out);
}